// Round 10
// baseline (267.932 us; speedup 1.0000x reference)
//
#include <hip/hip_runtime.h>
#include <cstdint>
#include <cstddef>

// Problem shape (fixed by the reference): B=8, S=2048, D=512, fp32 in/out.
#define B_ 8
#define S_ 2048
#define D_ 512

typedef float f32x4 __attribute__((ext_vector_type(4)));
typedef float f32x16 __attribute__((ext_vector_type(16)));
typedef __bf16 bf16x8 __attribute__((ext_vector_type(8)));

// fp32 -> bf16 round-to-nearest-even
__device__ __forceinline__ unsigned short f2bf(float f) {
    unsigned u = __builtin_bit_cast(unsigned, f);
    u += 0x7FFFu + ((u >> 16) & 1u);
    return (unsigned short)(u >> 16);
}

// async global->LDS, 16 B/lane; LDS dest = wave-uniform base + lane*16.
__device__ __forceinline__ void gll16(const void* g, void* l) {
    __builtin_amdgcn_global_load_lds(
        (const __attribute__((address_space(1))) unsigned int*)g,
        (__attribute__((address_space(3))) unsigned int*)l, 16, 0, 0);
}

#define VMCNT(n) asm volatile("s_waitcnt vmcnt(%0)" :: "i"(n) : "memory")
#define LGKM0()  asm volatile("s_waitcnt lgkmcnt(0)" ::: "memory")
#define SBAR()   __builtin_amdgcn_s_barrier()
#define SCHED0() __builtin_amdgcn_sched_barrier(0)

// ---------------------------------------------------------------------------
// gemm8<4,2> — r12's 4-phase counted-vmcnt pipeline, QKV projection only.
// Unchanged (passed, absmax 0.00195).
// ---------------------------------------------------------------------------
template<int AMT, int BNT>
__global__ __launch_bounds__(512, 2) void gemm8(
    const unsigned short* __restrict__ A,
    const unsigned short* __restrict__ B,
    void* __restrict__ Cv,
    unsigned short* __restrict__ Cv2,
    int K, int lda, int ldb, int ldc, int ntn)
{
    constexpr int BM     = 64 * AMT;
    constexpr int BN     = 128 * BNT;
    constexpr int ABYTES = BM * 128;          // per-buf A bytes (BK=64 bf16)
    constexpr int BBYTES = BN * 128;
    constexpr int AH     = ABYTES / 2;
    constexpr int BH     = BBYTES / 2;
    constexpr int AGL    = AMT / 2;           // glls per wave per A-half
    constexpr int BGL    = BNT;
    constexpr int BUFB   = ABYTES + BBYTES;
    __shared__ __align__(16) char lds[2 * BUFB];

    const int tq  = blockIdx.x;
    const int tn  = tq % ntn;
    const int tm  = tq / ntn;
    const int m0   = tm * BM;
    const int n0   = tn * BN;
    const int tid  = threadIdx.x;
    const int lane = tid & 63;
    const int w    = tid >> 6;
    const int g2   = w >> 2;
    const int nb   = w & 3;

    const int lrow = lane >> 3;
    const int swz  = ((lane & 7) ^ lrow) << 3;
    const unsigned short* gA[2][AGL];
    const unsigned short* gB[2][BGL];
    #pragma unroll
    for (int h = 0; h < 2; ++h) {
        #pragma unroll
        for (int i = 0; i < AGL; ++i)
            gA[h][i] = A + (size_t)(m0 + h * (BM / 2) + (w * AGL + i) * 8 + lrow) * lda + swz;
        #pragma unroll
        for (int i = 0; i < BGL; ++i)
            gB[h][i] = B + (size_t)(n0 + h * (BN / 2) + (w * BGL + i) * 8 + lrow) * ldb + swz;
    }
    auto stA = [&](int bs, int h, int kof) {
        #pragma unroll
        for (int i = 0; i < AGL; ++i)
            gll16(gA[h][i] + kof, lds + bs * BUFB + h * AH + (w * AGL + i) * 1024);
    };
    auto stB = [&](int bs, int h, int kof) {
        #pragma unroll
        for (int i = 0; i < BGL; ++i)
            gll16(gB[h][i] + kof, lds + bs * BUFB + ABYTES + h * BH + (w * BGL + i) * 1024);
    };

    const int fr = lane & 15;
    const int gq = lane >> 4;
    const int c0 = (gq ^ (fr & 7)) << 4;
    int aoff[AMT], boff[BNT];
    #pragma unroll
    for (int ml = 0; ml < AMT; ++ml)
        aoff[ml] = (g2 * (16 * AMT) + ml * 16 + fr) * 128 + c0;
    #pragma unroll
    for (int nl = 0; nl < BNT; ++nl)
        boff[nl] = (nb * (16 * BNT) + nl * 16 + fr) * 128 + c0;

    bf16x8 af[2 * AMT], bLO[2 * BNT], bHI[2 * BNT];
    f32x4 acc[2 * AMT][2 * BNT] = {};

    auto ldA = [&](const char* Ab, int mh) {
        #pragma unroll
        for (int ml = 0; ml < AMT; ++ml)
            #pragma unroll
            for (int kk = 0; kk < 2; ++kk)
                af[ml * 2 + kk] = *(const bf16x8*)(Ab + mh * AH + (aoff[ml] ^ (kk << 6)));
    };
    auto ldB = [&](const char* Bb, int nh, bf16x8* bf) {
        #pragma unroll
        for (int nl = 0; nl < BNT; ++nl)
            #pragma unroll
            for (int kk = 0; kk < 2; ++kk)
                bf[nl * 2 + kk] = *(const bf16x8*)(Bb + nh * BH + (boff[nl] ^ (kk << 6)));
    };
    auto mma = [&](int mh, int nh, const bf16x8* bf) {
        __builtin_amdgcn_s_setprio(1);
        #pragma unroll
        for (int ml = 0; ml < AMT; ++ml)
            #pragma unroll
            for (int nl = 0; nl < BNT; ++nl)
                #pragma unroll
                for (int kk = 0; kk < 2; ++kk)
                    acc[mh * AMT + ml][nh * BNT + nl] =
                        __builtin_amdgcn_mfma_f32_16x16x32_bf16(
                            af[ml * 2 + kk], bf[nl * 2 + kk],
                            acc[mh * AMT + ml][nh * BNT + nl], 0, 0, 0);
        __builtin_amdgcn_s_setprio(0);
    };

    stA(0, 0, 0);  stB(0, 0, 0);
    stA(0, 1, 0);  stB(0, 1, 0);
    stA(1, 0, 64); stB(1, 0, 64);

    const int NT = K >> 6;
    for (int tt = 0; tt < NT; ++tt) {
        const int bs = tt & 1;
        const char* Ab = lds + bs * BUFB;
        const char* Bb = Ab + ABYTES;
        const bool last = (tt == NT - 1);

        if (!last) stA(bs ^ 1, 1, (tt + 1) << 6);
        if (last) { VMCNT(AGL + BGL); } else { VMCNT(6); }
        SBAR(); SCHED0();
        ldA(Ab, 0); ldB(Bb, 0, bLO);
        mma(0, 0, bLO);

        if (!last) stB(bs ^ 1, 1, (tt + 1) << 6);
        if (last) { VMCNT(0); } else { VMCNT(6); }
        SBAR(); SCHED0();
        ldB(Bb, 1, bHI);
        mma(0, 1, bHI);

        if (tt + 2 < NT) stA(bs, 0, (tt + 2) << 6);
        VMCNT(6);
        SBAR(); SCHED0();
        ldA(Ab, 1);
        mma(1, 0, bLO);

        if (tt + 2 < NT) stB(bs, 0, (tt + 2) << 6);
        VMCNT(6);
        SBAR(); SCHED0();
        mma(1, 1, bHI);
    }

    const int rb4 = gq << 2;
#define AB_(mt) ((((mt) / AMT) * (BM / 2)) + g2 * (16 * AMT) + ((mt) % AMT) * 16)
#define BB_(nt) ((((nt) / BNT) * (BN / 2)) + nb * (16 * BNT) + ((nt) % BNT) * 16)
    if (tn >= 4) {
        #pragma unroll
        for (int mt = 0; mt < 2 * AMT; ++mt) {
            const int s0q = m0 + AB_(mt) + rb4;
            const int b   = s0q >> 11;
            const int se  = s0q & (S_ - 1);
            #pragma unroll
            for (int nt = 0; nt < 2 * BNT; ++nt) {
                const int d = (n0 - 2 * D_) + BB_(nt) + fr;
                ushort4 u;
                u.x = f2bf(acc[mt][nt][0]);
                u.y = f2bf(acc[mt][nt][1]);
                u.z = f2bf(acc[mt][nt][2]);
                u.w = f2bf(acc[mt][nt][3]);
                *(ushort4*)&Cv2[((size_t)b * D_ + d) * S_ + se] = u;
            }
        }
    } else {
        unsigned short* C = (unsigned short*)Cv;
        #pragma unroll
        for (int mt = 0; mt < 2 * AMT; ++mt)
            #pragma unroll
            for (int nt = 0; nt < 2 * BNT; ++nt) {
                const int gc = n0 + BB_(nt) + fr;
                #pragma unroll
                for (int r = 0; r < 4; ++r)
                    C[(size_t)(m0 + AB_(mt) + rb4 + r) * ldc + gc] = f2bf(acc[mt][nt][r]);
            }
    }
#undef AB_
#undef BB_
}

// ---------------------------------------------------------------------------
// fused_attn v5 — 32x32x16 MFMA: halve LDS reads per FLOP.
//
// r20 post-mortem: v4 clean (FETCH 25MB, WRITE 34MB, no spill) at 107us but
// LDS-PIPE BOUND: per kv-tile 16.1K cyc = LDS 10.7K (896 b128 x 12cyc/CU)
// + conflicts 3.7K vs MFMA 4.1K. Fix = 32x32x16 MFMA: same 16B/lane operand
// reads, 2x FLOP each -> reads/FLOP halve. Per wave/tile: 112 -> 80 b128
// (S 64->32 via Q-in-reg B-operand; PV 48: wave owns d-blocks {w, w+8} x
// 2 q-blocks, V-frag feeds 2 MFMAs). LDS floor 10.7K -> 7.7K.
//
// Layouts (32x32x16): A[row=lane&31][k=(lane>>5)*8+j], B symmetric;
// C/D col=lane&31, row=(reg&3)+8*(reg>>2)+4*(lane>>5)  [m74/m101 HW-verified].
// S-phase: waves (g4=kv-32-block 0..3) x (qh=q-32-half): S^T[kv32][q32] =
//   mfma(K-frag, qreg), 8 steps/128-d chunk, acc_s f32x16.
// P pack: regs 4k..4k+3 = kv (g4*32 + 8k + 4*hi) + 0..3 -> ushort4 at
//   chunk (4*g4+k)^(fr32&7), half hi.  One writer/slot; 2-way-free banks.
// PV: A=V^T-frag (row=d), B=P-frag (col=q, row-addressed by q in PB);
//   PV-a = d-blocks 0-7 (V0 slot0 waves 0-3, V1 slot1 waves 4-7);
//   PV-b = d-blocks 8-15 (V2/V3). acc = 4 x f32x16.
// O-store: reg-quads = 4 consecutive d -> float4 stores (16/lane).
// Staging/ring/vmcnt chain BYTE-IDENTICAL to v4 (reads/phase are a subset
// -> verified force + WAR chains carry over):
//   stage:  P0:K2 | P1:K3,V0 | P2:V1 | P3:V2 | P4:V3 | P5:K0',K1'
//   vmcnt:  P0:4  | P1:4     | P2:8  | P3:8  | P4:4  | P5:0
// Regs: qreg 64 + acc 80 + transients ~30 ≈ 175 unified (envelope-safe).
// Math identical (absmax 0.00195): no-max-sub exp, bf16 P, fp32 accum.
// LDS: ring 4x32K @0 | P 16K @131072 | RS 1K @147456 = 148480.
// Grid: 8 batches (XCD-pinned) x 32 q-panels = 256 blocks, 8 waves.
// ---------------------------------------------------------------------------
__global__ __launch_bounds__(512, 2) void fused_attn(
    const unsigned short* __restrict__ qk,   // [B*S][1024] rows: Q|K
    const unsigned short* __restrict__ vtb,  // [B][512][2048] = V^T
    float* __restrict__ out,                 // [B][S][512]
    float scale)
{
    __shared__ __align__(16) char lds[148480];
    char* const RING = lds;                       // 4 x 32KB chunk slots
    char* const PB   = lds + 131072;              // P [64 q][128 kv], 256B rows
    float* const RS  = (float*)(lds + 147456);    // rs[4 g4][64 q]

    const int lin = blockIdx.x;
    const int bz  = lin & 7;                      // batch -> XCD pin
    const int q0  = (lin >> 3) * 64;              // q-panel base
    const int tid = threadIdx.x;
    const int lane = tid & 63;
    const int w    = tid >> 6;
    const int fr32 = lane & 31;
    const int hi   = lane >> 5;
    const int g4   = w >> 1;                      // kv 32-block (S-phase)
    const int qh   = w & 1;                       // q 32-half   (S-phase)
    const int k7x  = fr32 & 7;

    // 256B-row staging geometry: off = tid*16 + i*8192.
    int row4[4], sc4[4];
    #pragma unroll
    for (int i = 0; i < 4; ++i) {
        const int off = tid * 16 + i * 8192;
        row4[i] = off >> 8;
        sc4[i]  = ((((off >> 4) & 15) ^ (row4[i] & 7)) << 3);
    }
    const size_t qrowb = (size_t)bz * S_;

    auto stK = [&](int slot, int kv0, int j) {    // K chunk j: [128 kv][128 d]
        #pragma unroll
        for (int i = 0; i < 4; ++i)
            gll16(qk + (qrowb + kv0 + row4[i]) * 1024 + 512 + j * 128 + sc4[i],
                  RING + slot * 32768 + tid * 16 + i * 8192);
    };
    auto stV = [&](int slot, int kv0, int c) {    // V chunk c: [128 d][128 kv]
        #pragma unroll
        for (int i = 0; i < 4; ++i)
            gll16(vtb + ((size_t)bz * D_ + c * 128 + row4[i]) * S_ + kv0 + sc4[i],
                  RING + slot * 32768 + tid * 16 + i * 8192);
    };

    // ---- Q -> registers: qreg[c] = B-frag, q=qh*32+fr32, d=c*16+hi*8.. ----
    bf16x8 qreg[32];
    #pragma unroll
    for (int c = 0; c < 32; ++c)
        qreg[c] = *(const bf16x8*)(
            qk + (qrowb + q0 + qh * 32 + fr32) * 1024 + c * 16 + hi * 8);
    SCHED0();

    f32x16 accA0 = {}, accA1 = {}, accB0 = {}, accB1 = {};
    float rsl = 0.f;

    stK(0, 0, 0); stK(1, 0, 1);                   // prologue: K0->s0, K1->s1
    SCHED0();

    for (int kvi = 0; kvi < 16; ++kvi) {
        const int kv0 = kvi * 128;
        f32x16 acc_s = {};

        // ---- S-phases j=0..3: 8 kf reads + 8 MFMA each ----
        #pragma unroll
        for (int j = 0; j < 4; ++j) {
            if (j < 2) { VMCNT(4); } else { VMCNT(8); }
            SBAR(); SCHED0();
            if      (j == 0) stK(2, kv0, 2);
            else if (j == 1) { stK(3, kv0, 3); stV(0, kv0, 0); }
            else if (j == 2) stV(1, kv0, 1);
            else             stV(2, kv0, 2);
            SCHED0();
            const char* Kb = RING + j * 32768;
            __builtin_amdgcn_s_setprio(1);
            #pragma unroll
            for (int c = 0; c < 8; ++c) {
                const int ch = (((c << 1) | hi) ^ k7x) << 4;
                const bf16x8 kf = *(const bf16x8*)(
                    Kb + (g4 * 32 + fr32) * 256 + ch);
                acc_s = __builtin_amdgcn_mfma_f32_32x32x16_bf16(
                    kf, qreg[j * 8 + c], acc_s, 0, 0, 0);
            }
            __builtin_amdgcn_s_setprio(0);
        }

        // ---- P4 (PV-a): exp + P-write | force V0,V1 | stage V3 ----
        #pragma unroll
        for (int k = 0; k < 4; ++k) {
            float p0 = __expf(acc_s[4 * k + 0] * scale);
            float p1 = __expf(acc_s[4 * k + 1] * scale);
            float p2 = __expf(acc_s[4 * k + 2] * scale);
            float p3 = __expf(acc_s[4 * k + 3] * scale);
            rsl += (p0 + p1) + (p2 + p3);
            ushort4 u;
            u.x = f2bf(p0); u.y = f2bf(p1); u.z = f2bf(p2); u.w = f2bf(p3);
            const int chunk = 4 * g4 + k;
            *(ushort4*)(PB + (qh * 32 + fr32) * 256 +
                        ((chunk ^ k7x) << 4) + hi * 8) = u;
        }
        LGKM0();           // my P writes visible
        VMCNT(4);          // force V0,V1 (leaves V2 flying)
        SBAR(); SCHED0();  // everyone's P + V0,V1 ready
        stV(3, kv0, 3);
        SCHED0();
        // PV-a: d-block w (chunk w>>2): waves 0-3 slot0, 4-7 slot1
        {
            const char* Va = RING + (w >> 2) * 32768;
            const int vrow = ((w & 3) * 32 + fr32) * 256;
            __builtin_amdgcn_s_setprio(1);
            #pragma unroll
            for (int ks = 0; ks < 8; ++ks) {
                const int ch = (((ks << 1) | hi) ^ k7x) << 4;
                const bf16x8 vf  = *(const bf16x8*)(Va + vrow + ch);
                const bf16x8 pf0 = *(const bf16x8*)(PB + fr32 * 256 + ch);
                const bf16x8 pf1 = *(const bf16x8*)(PB + (32 + fr32) * 256 + ch);
                accA0 = __builtin_amdgcn_mfma_f32_32x32x16_bf16(vf, pf0, accA0, 0, 0, 0);
                accA1 = __builtin_amdgcn_mfma_f32_32x32x16_bf16(vf, pf1, accA1, 0, 0, 0);
            }
            __builtin_amdgcn_s_setprio(0);
        }

        // ---- P5 (PV-b): exact drain V2,V3 | stage K0',K1' ----
        VMCNT(0);
        SBAR(); SCHED0();
        if (kvi < 15) { stK(0, kv0 + 128, 0); stK(1, kv0 + 128, 1); }
        SCHED0();
        // PV-b: d-block w+8 (chunk 2+(w>>2)): waves 0-3 slot2, 4-7 slot3
        {
            const char* Vb = RING + (2 + (w >> 2)) * 32768;
            const int vrow = ((w & 3) * 32 + fr32) * 256;
            __builtin_amdgcn_s_setprio(1);
            #pragma unroll
            for (int ks = 0; ks < 8; ++ks) {
                const int ch = (((ks << 1) | hi) ^ k7x) << 4;
                const bf16x8 vf  = *(const bf16x8*)(Vb + vrow + ch);
                const bf16x8 pf0 = *(const bf16x8*)(PB + fr32 * 256 + ch);
                const bf16x8 pf1 = *(const bf16x8*)(PB + (32 + fr32) * 256 + ch);
                accB0 = __builtin_amdgcn_mfma_f32_32x32x16_bf16(vf, pf0, accB0, 0, 0, 0);
                accB1 = __builtin_amdgcn_mfma_f32_32x32x16_bf16(vf, pf1, accB1, 0, 0, 0);
            }
            __builtin_amdgcn_s_setprio(0);
        }
    }

    // ---- rowsum reduce: fold hi; RS[g4][q], unique writers ----
    rsl += __shfl_xor(rsl, 32);
    if (lane < 32) RS[g4 * 64 + qh * 32 + fr32] = rsl;
    __syncthreads();

    // ---- normalize + store O[b][q0+q][d], float4 along d ----
    // tile (dblk, qblk): dblk=w -> accA*, dblk=w+8 -> accB*; d from reg-quads.
#define STORE_TILE(ACC, DBASE, QB)                                          \
    {                                                                       \
        const int q = (QB) * 32 + fr32;                                     \
        const float inv = __builtin_amdgcn_rcpf(                            \
            (RS[q] + RS[64 + q]) + (RS[128 + q] + RS[192 + q]));            \
        float* op = out + ((qrowb + q0 + q) * D_);                          \
        _Pragma("unroll")                                                   \
        for (int k = 0; k < 4; ++k) {                                       \
            const int d0 = (DBASE) * 32 + 8 * k + 4 * hi;                   \
            float4 o;                                                       \
            o.x = (ACC)[4 * k + 0] * inv;                                   \
            o.y = (ACC)[4 * k + 1] * inv;                                   \
            o.z = (ACC)[4 * k + 2] * inv;                                   \
            o.w = (ACC)[4 * k + 3] * inv;                                   \
            *(float4*)(op + d0) = o;                                        \
        }                                                                   \
    }
    STORE_TILE(accA0, w,     0)
    STORE_TILE(accA1, w,     1)
    STORE_TILE(accB0, w + 8, 0)
    STORE_TILE(accB1, w + 8, 1)
#undef STORE_TILE
}

// ---------------------------------------------------------------------------
// fp32 -> bf16 convert, 4 elems/thread
// ---------------------------------------------------------------------------
__global__ __launch_bounds__(256) void convert_x4(const float* __restrict__ x,
                                                  unsigned short* __restrict__ xb) {
    const size_t i = ((size_t)blockIdx.x * 256 + threadIdx.x) * 4;
    const float4 f = *(const float4*)(x + i);
    ushort4 u;
    u.x = f2bf(f.x); u.y = f2bf(f.y); u.z = f2bf(f.z); u.w = f2bf(f.w);
    *(ushort4*)(xb + i) = u;
}

// W [D][D] (d,e) -> WT bf16 rows e (n), cols d (k); WQ|WK|WV stack to [3D][D].
__global__ __launch_bounds__(256) void convert_w(const float* __restrict__ WQ,
                                                 const float* __restrict__ WK,
                                                 const float* __restrict__ WV,
                                                 unsigned short* __restrict__ WT) {
    const int o = blockIdx.x * 256 + threadIdx.x;   // 0..D*D-1
    const float* W = blockIdx.y == 0 ? WQ : (blockIdx.y == 1 ? WK : WV);
    const int e = o >> 9, d = o & (D_ - 1);
    WT[(size_t)blockIdx.y * D_ * D_ + o] = f2bf(W[d * D_ + e]);
}

// ---------------------------------------------------------------------------
extern "C" void kernel_launch(void* const* d_in, const int* in_sizes, int n_in,
                              void* d_out, int out_size, void* d_ws, size_t ws_size,
                              hipStream_t stream)
{
    const float* x  = (const float*)d_in[0];
    const float* WQ = (const float*)d_in[1];
    const float* WK = (const float*)d_in[2];
    const float* WV = (const float*)d_in[3];

    // workspace layout (bf16 elements); ~103 MB total
    unsigned short* ws  = (unsigned short*)d_ws;
    const size_t NX = (size_t)B_ * S_ * D_;          // 8,388,608
    unsigned short* xb  = ws;                        // [16384][512]
    unsigned short* wtb = xb + NX;                   // [1536 n][512 k]
    unsigned short* qk  = wtb + 3 * D_ * D_;         // [16384][1024] (Q|K)
    unsigned short* vtb = qk + NX * 2;               // [b][d][s] = V^T

    // 1) converts
    convert_x4<<<dim3((unsigned)(NX / 4 / 256)), 256, 0, stream>>>(x, xb);
    convert_w<<<dim3(D_ * D_ / 256, 3), 256, 0, stream>>>(WQ, WK, WV, wtb);

    // 2) fused QKV projection, 256x256 tiles: grid 64 x 6 = 384.
    //    tn 0-3: Q|K -> qk; tn 4-5: V -> vtb transposed.
    gemm8<4, 2><<<dim3(384), 512, 0, stream>>>(
        xb, wtb, qk, vtb, D_, D_, D_, 2 * D_, /*ntn*/ 6);

    // 3) fused attention: scores + exp + rowsum + PV + normalize.
    //    8 batches x 32 q-panels = 256 blocks = 1 full round.
    fused_attn<<<dim3(256), 512, 0, stream>>>(
        qk, vtb, (float*)d_out, 0.04419417382415922f);
}

// Round 11
// 238.890 us; speedup vs baseline: 1.1216x; 1.1216x over previous
//
#include <hip/hip_runtime.h>
#include <cstdint>
#include <cstddef>

// Problem shape (fixed by the reference): B=8, S=2048, D=512, fp32 in/out.
#define B_ 8
#define S_ 2048
#define D_ 512

typedef float f32x4 __attribute__((ext_vector_type(4)));
typedef __bf16 bf16x8 __attribute__((ext_vector_type(8)));

// fp32 -> bf16 round-to-nearest-even
__device__ __forceinline__ unsigned short f2bf(float f) {
    unsigned u = __builtin_bit_cast(unsigned, f);
    u += 0x7FFFu + ((u >> 16) & 1u);
    return (unsigned short)(u >> 16);
}

// async global->LDS, 16 B/lane; LDS dest = wave-uniform base + lane*16.
__device__ __forceinline__ void gll16(const void* g, void* l) {
    __builtin_amdgcn_global_load_lds(
        (const __attribute__((address_space(1))) unsigned int*)g,
        (__attribute__((address_space(3))) unsigned int*)l, 16, 0, 0);
}

#define VMCNT(n) asm volatile("s_waitcnt vmcnt(%0)" :: "i"(n) : "memory")
#define LGKM0()  asm volatile("s_waitcnt lgkmcnt(0)" ::: "memory")
#define SBAR()   __builtin_amdgcn_s_barrier()
#define SCHED0() __builtin_amdgcn_sched_barrier(0)

// ---------------------------------------------------------------------------
// gemm8<4,2> — r12's 4-phase counted-vmcnt pipeline, QKV projection only.
// Unchanged (passed, absmax 0.00195).
// ---------------------------------------------------------------------------
template<int AMT, int BNT>
__global__ __launch_bounds__(512, 2) void gemm8(
    const unsigned short* __restrict__ A,
    const unsigned short* __restrict__ B,
    void* __restrict__ Cv,
    unsigned short* __restrict__ Cv2,
    int K, int lda, int ldb, int ldc, int ntn)
{
    constexpr int BM     = 64 * AMT;
    constexpr int BN     = 128 * BNT;
    constexpr int ABYTES = BM * 128;          // per-buf A bytes (BK=64 bf16)
    constexpr int BBYTES = BN * 128;
    constexpr int AH     = ABYTES / 2;
    constexpr int BH     = BBYTES / 2;
    constexpr int AGL    = AMT / 2;           // glls per wave per A-half
    constexpr int BGL    = BNT;
    constexpr int BUFB   = ABYTES + BBYTES;
    __shared__ __align__(16) char lds[2 * BUFB];

    const int tq  = blockIdx.x;
    const int tn  = tq % ntn;
    const int tm  = tq / ntn;
    const int m0   = tm * BM;
    const int n0   = tn * BN;
    const int tid  = threadIdx.x;
    const int lane = tid & 63;
    const int w    = tid >> 6;
    const int g2   = w >> 2;
    const int nb   = w & 3;

    const int lrow = lane >> 3;
    const int swz  = ((lane & 7) ^ lrow) << 3;
    const unsigned short* gA[2][AGL];
    const unsigned short* gB[2][BGL];
    #pragma unroll
    for (int h = 0; h < 2; ++h) {
        #pragma unroll
        for (int i = 0; i < AGL; ++i)
            gA[h][i] = A + (size_t)(m0 + h * (BM / 2) + (w * AGL + i) * 8 + lrow) * lda + swz;
        #pragma unroll
        for (int i = 0; i < BGL; ++i)
            gB[h][i] = B + (size_t)(n0 + h * (BN / 2) + (w * BGL + i) * 8 + lrow) * ldb + swz;
    }
    auto stA = [&](int bs, int h, int kof) {
        #pragma unroll
        for (int i = 0; i < AGL; ++i)
            gll16(gA[h][i] + kof, lds + bs * BUFB + h * AH + (w * AGL + i) * 1024);
    };
    auto stB = [&](int bs, int h, int kof) {
        #pragma unroll
        for (int i = 0; i < BGL; ++i)
            gll16(gB[h][i] + kof, lds + bs * BUFB + ABYTES + h * BH + (w * BGL + i) * 1024);
    };

    const int fr = lane & 15;
    const int gq = lane >> 4;
    const int c0 = (gq ^ (fr & 7)) << 4;
    int aoff[AMT], boff[BNT];
    #pragma unroll
    for (int ml = 0; ml < AMT; ++ml)
        aoff[ml] = (g2 * (16 * AMT) + ml * 16 + fr) * 128 + c0;
    #pragma unroll
    for (int nl = 0; nl < BNT; ++nl)
        boff[nl] = (nb * (16 * BNT) + nl * 16 + fr) * 128 + c0;

    bf16x8 af[2 * AMT], bLO[2 * BNT], bHI[2 * BNT];
    f32x4 acc[2 * AMT][2 * BNT] = {};

    auto ldA = [&](const char* Ab, int mh) {
        #pragma unroll
        for (int ml = 0; ml < AMT; ++ml)
            #pragma unroll
            for (int kk = 0; kk < 2; ++kk)
                af[ml * 2 + kk] = *(const bf16x8*)(Ab + mh * AH + (aoff[ml] ^ (kk << 6)));
    };
    auto ldB = [&](const char* Bb, int nh, bf16x8* bf) {
        #pragma unroll
        for (int nl = 0; nl < BNT; ++nl)
            #pragma unroll
            for (int kk = 0; kk < 2; ++kk)
                bf[nl * 2 + kk] = *(const bf16x8*)(Bb + nh * BH + (boff[nl] ^ (kk << 6)));
    };
    auto mma = [&](int mh, int nh, const bf16x8* bf) {
        __builtin_amdgcn_s_setprio(1);
        #pragma unroll
        for (int ml = 0; ml < AMT; ++ml)
            #pragma unroll
            for (int nl = 0; nl < BNT; ++nl)
                #pragma unroll
                for (int kk = 0; kk < 2; ++kk)
                    acc[mh * AMT + ml][nh * BNT + nl] =
                        __builtin_amdgcn_mfma_f32_16x16x32_bf16(
                            af[ml * 2 + kk], bf[nl * 2 + kk],
                            acc[mh * AMT + ml][nh * BNT + nl], 0, 0, 0);
        __builtin_amdgcn_s_setprio(0);
    };

    stA(0, 0, 0);  stB(0, 0, 0);
    stA(0, 1, 0);  stB(0, 1, 0);
    stA(1, 0, 64); stB(1, 0, 64);

    const int NT = K >> 6;
    for (int tt = 0; tt < NT; ++tt) {
        const int bs = tt & 1;
        const char* Ab = lds + bs * BUFB;
        const char* Bb = Ab + ABYTES;
        const bool last = (tt == NT - 1);

        if (!last) stA(bs ^ 1, 1, (tt + 1) << 6);
        if (last) { VMCNT(AGL + BGL); } else { VMCNT(6); }
        SBAR(); SCHED0();
        ldA(Ab, 0); ldB(Bb, 0, bLO);
        mma(0, 0, bLO);

        if (!last) stB(bs ^ 1, 1, (tt + 1) << 6);
        if (last) { VMCNT(0); } else { VMCNT(6); }
        SBAR(); SCHED0();
        ldB(Bb, 1, bHI);
        mma(0, 1, bHI);

        if (tt + 2 < NT) stA(bs, 0, (tt + 2) << 6);
        VMCNT(6);
        SBAR(); SCHED0();
        ldA(Ab, 1);
        mma(1, 0, bLO);

        if (tt + 2 < NT) stB(bs, 0, (tt + 2) << 6);
        VMCNT(6);
        SBAR(); SCHED0();
        mma(1, 1, bHI);
    }

    const int rb4 = gq << 2;
#define AB_(mt) ((((mt) / AMT) * (BM / 2)) + g2 * (16 * AMT) + ((mt) % AMT) * 16)
#define BB_(nt) ((((nt) / BNT) * (BN / 2)) + nb * (16 * BNT) + ((nt) % BNT) * 16)
    if (tn >= 4) {
        #pragma unroll
        for (int mt = 0; mt < 2 * AMT; ++mt) {
            const int s0q = m0 + AB_(mt) + rb4;
            const int b   = s0q >> 11;
            const int se  = s0q & (S_ - 1);
            #pragma unroll
            for (int nt = 0; nt < 2 * BNT; ++nt) {
                const int d = (n0 - 2 * D_) + BB_(nt) + fr;
                ushort4 u;
                u.x = f2bf(acc[mt][nt][0]);
                u.y = f2bf(acc[mt][nt][1]);
                u.z = f2bf(acc[mt][nt][2]);
                u.w = f2bf(acc[mt][nt][3]);
                *(ushort4*)&Cv2[((size_t)b * D_ + d) * S_ + se] = u;
            }
        }
    } else {
        unsigned short* C = (unsigned short*)Cv;
        #pragma unroll
        for (int mt = 0; mt < 2 * AMT; ++mt)
            #pragma unroll
            for (int nt = 0; nt < 2 * BNT; ++nt) {
                const int gc = n0 + BB_(nt) + fr;
                #pragma unroll
                for (int r = 0; r < 4; ++r)
                    C[(size_t)(m0 + AB_(mt) + rb4 + r) * ldc + gc] = f2bf(acc[mt][nt][r]);
            }
    }
#undef AB_
#undef BB_
}

// ---------------------------------------------------------------------------
// fused_attn v6 = v4 (round-9, clean 107.7us) + pf-register-holding.
//
// r21 post-mortem: v5's qreg[32]=128 VGPR spilled (FETCH 48.7/WRITE 70.1MB,
// 153us) — 32x32 B-operand inherently needs the full 512-d q-row per lane.
// Empirical law (r18/r19/r21): arch-VGPR demand >~130 spills; v4 (~110) is
// clean. 32x32 also does NOT reduce PV reads (48 either way) — dead end.
//
// v6 change vs v4 (one lever): the 16 pf frags are read TWICE from P-LDS
// (PV-a for V0/V1, PV-b for V2/V3) = 32 of 112 b128/wave/tile. Hoist into
// pf[4][4] (64 VGPR, tile-local, static idx) -> reads 112 -> 96 (-14% of
// the 10.7K-cyc LDS floor). Register plan: qreg 64 + pf 64 + transients
// ~35 = ~160 arch + 80 acc = 240 unified <= 256 @ 2 waves/SIMD; bound
// (512,1) since occupancy is LDS-pinned at 1 block/CU anyway.
// NO-SPILL CHECK next round: FETCH must stay ~25MB, WRITE ~34MB.
//
// Everything else byte-identical to round 9: 6 phases/tile, ring-4,
//   stage:  P0:K2 | P1:K3,V0 | P2:V1 | P3:V2 | P4:V3 | P5:K0',K1'
//   vmcnt:  P0:4  | P1:4     | P2:8  | P3:8  | P4:4  | P5:0
// Math identical (absmax 0.00195): no-max-sub exp, bf16 P, fp32 accum.
// LDS: ring 4x32K @0 | P 16K @131072 | RS 512B @147456.
// Grid: 8 batches (XCD-pinned) x 32 q-panels = 256 blocks, 8 waves.
// ---------------------------------------------------------------------------
__global__ __launch_bounds__(512, 1) void fused_attn(
    const unsigned short* __restrict__ qk,   // [B*S][1024] rows: Q|K
    const unsigned short* __restrict__ vtb,  // [B][512][2048] = V^T
    float* __restrict__ out,                 // [B][S][512]
    float scale)
{
    __shared__ __align__(16) char lds[148480];
    char* const RING = lds;                       // 4 x 32KB chunk slots
    char* const PB   = lds + 131072;              // P [64 q][128 kv], 256B rows
    float* const RS  = (float*)(lds + 147456);    // rs[2][64]

    const int lin = blockIdx.x;
    const int bz  = lin & 7;                      // batch -> XCD pin
    const int q0  = (lin >> 3) * 64;              // q-panel base
    const int tid = threadIdx.x;
    const int lane = tid & 63;
    const int w   = tid >> 6;
    const int fr  = lane & 15;
    const int gq  = lane >> 4;
    const int g2  = w >> 2;                       // kv-half (S-phase)
    const int nb  = w & 3;                        // q-quarter (S-phase)
    const int k7  = fr & 7;

    // 256B-row staging geometry: off = tid*16 + i*8192.
    int row4[4], sc4[4];
    #pragma unroll
    for (int i = 0; i < 4; ++i) {
        const int off = tid * 16 + i * 8192;
        row4[i] = off >> 8;
        sc4[i]  = ((((off >> 4) & 15) ^ (row4[i] & 7)) << 3);
    }
    const size_t qrowb = (size_t)bz * S_;

    auto stK = [&](int slot, int kv0, int j) {    // K chunk j: [128 kv][128 d]
        #pragma unroll
        for (int i = 0; i < 4; ++i)
            gll16(qk + (qrowb + kv0 + row4[i]) * 1024 + 512 + j * 128 + sc4[i],
                  RING + slot * 32768 + tid * 16 + i * 8192);
    };
    auto stV = [&](int slot, int kv0, int c) {    // V chunk c: [128 d][128 kv]
        #pragma unroll
        for (int i = 0; i < 4; ++i)
            gll16(vtb + ((size_t)bz * D_ + c * 128 + row4[i]) * S_ + kv0 + sc4[i],
                  RING + slot * 32768 + tid * 16 + i * 8192);
    };

    // ---- Q -> registers: qreg[c] = B-frag [col=q=nb*16+fr][k-chunk c] ----
    bf16x8 qreg[16];
    #pragma unroll
    for (int c = 0; c < 16; ++c)
        qreg[c] = *(const bf16x8*)(
            qk + (qrowb + q0 + nb * 16 + fr) * 1024 + c * 32 + gq * 8);
    SCHED0();

    f32x4 acc_pv[4][4] = {};                      // [d-chunk][q-16-block]
    float rsl = 0.f;

    stK(0, 0, 0); stK(1, 0, 1);                   // prologue: K0->s0, K1->s1
    SCHED0();

    for (int kvi = 0; kvi < 16; ++kvi) {
        const int kv0 = kvi * 128;
        f32x4 acc_s[4] = {};                      // [mt: kv16-block in half]

        // ---- S-phases j=0..3 ----
        #pragma unroll
        for (int j = 0; j < 4; ++j) {
            if (j < 2) { VMCNT(4); } else { VMCNT(8); }
            SBAR(); SCHED0();
            if      (j == 0) stK(2, kv0, 2);
            else if (j == 1) { stK(3, kv0, 3); stV(0, kv0, 0); }
            else if (j == 2) stV(1, kv0, 1);
            else             stV(2, kv0, 2);
            SCHED0();
            const char* Kb = RING + j * 32768;
            __builtin_amdgcn_s_setprio(1);
            #pragma unroll
            for (int kk = 0; kk < 4; ++kk) {
                const int ch = ((kk * 4 + gq) ^ k7) << 4;
                #pragma unroll
                for (int mt = 0; mt < 4; ++mt) {
                    const bf16x8 kf = *(const bf16x8*)(
                        Kb + (g2 * 64 + mt * 16 + fr) * 256 + ch);
                    acc_s[mt] = __builtin_amdgcn_mfma_f32_16x16x32_bf16(
                        kf, qreg[j * 4 + kk], acc_s[mt], 0, 0, 0);
                }
            }
            __builtin_amdgcn_s_setprio(0);
        }

        // ---- P4 (PV-a): exp + P-write | force V0,V1 | stage V3 ----
        #pragma unroll
        for (int mt = 0; mt < 4; ++mt) {
            float p0 = __expf(acc_s[mt][0] * scale);
            float p1 = __expf(acc_s[mt][1] * scale);
            float p2 = __expf(acc_s[mt][2] * scale);
            float p3 = __expf(acc_s[mt][3] * scale);
            rsl += (p0 + p1) + (p2 + p3);
            ushort4 u;
            u.x = f2bf(p0); u.y = f2bf(p1); u.z = f2bf(p2); u.w = f2bf(p3);
            const int row   = nb * 16 + fr;
            const int chunk = g2 * 8 + mt * 2 + (gq >> 1);
            *(ushort4*)(PB + row * 256 + ((chunk ^ k7) << 4) + (gq & 1) * 8) = u;
        }
        LGKM0();           // my P writes visible
        VMCNT(4);          // force V0,V1 (leaves V2,V3-slot flying)
        SBAR(); SCHED0();  // everyone's P + V0,V1 ready
        stV(3, kv0, 3);
        SCHED0();

        // ---- pf: read ALL 16 P-frags ONCE; reused by PV-a AND PV-b ----
        bf16x8 pf[4][4];
        #pragma unroll
        for (int nt2 = 0; nt2 < 4; ++nt2)
            #pragma unroll
            for (int ks = 0; ks < 4; ++ks)
                pf[nt2][ks] = *(const bf16x8*)(
                    PB + (nt2 * 16 + fr) * 256 + (((ks * 4 + gq) ^ k7) << 4));

        __builtin_amdgcn_s_setprio(1);
        #pragma unroll
        for (int ks = 0; ks < 4; ++ks) {
            const int ch = ((ks * 4 + gq) ^ k7) << 4;
            const bf16x8 vf0 = *(const bf16x8*)(RING + (w * 16 + fr) * 256 + ch);
            const bf16x8 vf1 = *(const bf16x8*)(RING + 32768 + (w * 16 + fr) * 256 + ch);
            #pragma unroll
            for (int nt2 = 0; nt2 < 4; ++nt2) {
                acc_pv[0][nt2] = __builtin_amdgcn_mfma_f32_16x16x32_bf16(
                    vf0, pf[nt2][ks], acc_pv[0][nt2], 0, 0, 0);
                acc_pv[1][nt2] = __builtin_amdgcn_mfma_f32_16x16x32_bf16(
                    vf1, pf[nt2][ks], acc_pv[1][nt2], 0, 0, 0);
            }
        }
        __builtin_amdgcn_s_setprio(0);

        // ---- P5 (PV-b): exact drain V2,V3 | stage K0',K1' | pf from regs ----
        VMCNT(0);
        SBAR(); SCHED0();
        if (kvi < 15) { stK(0, kv0 + 128, 0); stK(1, kv0 + 128, 1); }
        SCHED0();
        __builtin_amdgcn_s_setprio(1);
        #pragma unroll
        for (int ks = 0; ks < 4; ++ks) {
            const int ch = ((ks * 4 + gq) ^ k7) << 4;
            const bf16x8 vf2 = *(const bf16x8*)(RING + 65536 + (w * 16 + fr) * 256 + ch);
            const bf16x8 vf3 = *(const bf16x8*)(RING + 98304 + (w * 16 + fr) * 256 + ch);
            #pragma unroll
            for (int nt2 = 0; nt2 < 4; ++nt2) {
                acc_pv[2][nt2] = __builtin_amdgcn_mfma_f32_16x16x32_bf16(
                    vf2, pf[nt2][ks], acc_pv[2][nt2], 0, 0, 0);
                acc_pv[3][nt2] = __builtin_amdgcn_mfma_f32_16x16x32_bf16(
                    vf3, pf[nt2][ks], acc_pv[3][nt2], 0, 0, 0);
            }
        }
        __builtin_amdgcn_s_setprio(0);
    }

    // ---- rowsum reduce: fold gq axis; RS[g2][q], unique writers ----
    rsl += __shfl_xor(rsl, 16);
    rsl += __shfl_xor(rsl, 32);
    if (lane < 16) RS[g2 * 64 + nb * 16 + lane] = rsl;
    __syncthreads();

    // ---- normalize + store O[b][q0+q][d], float4 along d ----
    #pragma unroll
    for (int nt2 = 0; nt2 < 4; ++nt2) {
        const int q = nt2 * 16 + fr;
        const float inv = __builtin_amdgcn_rcpf(RS[q] + RS[64 + q]);
        float* op = out + ((qrowb + q0 + q) * D_);
        #pragma unroll
        for (int c = 0; c < 4; ++c) {
            const int d0 = c * 128 + w * 16 + gq * 4;
            float4 o;
            o.x = acc_pv[c][nt2][0] * inv;
            o.y = acc_pv[c][nt2][1] * inv;
            o.z = acc_pv[c][nt2][2] * inv;
            o.w = acc_pv[c][nt2][3] * inv;
            *(float4*)(op + d0) = o;
        }
    }
}

// ---------------------------------------------------------------------------
// fp32 -> bf16 convert, 4 elems/thread
// ---------------------------------------------------------------------------
__global__ __launch_bounds__(256) void convert_x4(const float* __restrict__ x,
                                                  unsigned short* __restrict__ xb) {
    const size_t i = ((size_t)blockIdx.x * 256 + threadIdx.x) * 4;
    const float4 f = *(const float4*)(x + i);
    ushort4 u;
    u.x = f2bf(f.x); u.y = f2bf(f.y); u.z = f2bf(f.z); u.w = f2bf(f.w);
    *(ushort4*)(xb + i) = u;
}

// W [D][D] (d,e) -> WT bf16 rows e (n), cols d (k); WQ|WK|WV stack to [3D][D].
__global__ __launch_bounds__(256) void convert_w(const float* __restrict__ WQ,
                                                 const float* __restrict__ WK,
                                                 const float* __restrict__ WV,
                                                 unsigned short* __restrict__ WT) {
    const int o = blockIdx.x * 256 + threadIdx.x;   // 0..D*D-1
    const float* W = blockIdx.y == 0 ? WQ : (blockIdx.y == 1 ? WK : WV);
    const int e = o >> 9, d = o & (D_ - 1);
    WT[(size_t)blockIdx.y * D_ * D_ + o] = f2bf(W[d * D_ + e]);
}

// ---------------------------------------------------------------------------
extern "C" void kernel_launch(void* const* d_in, const int* in_sizes, int n_in,
                              void* d_out, int out_size, void* d_ws, size_t ws_size,
                              hipStream_t stream)
{
    const float* x  = (const float*)d_in[0];
    const float* WQ = (const float*)d_in[1];
    const float* WK = (const float*)d_in[2];
    const float* WV = (const float*)d_in[3];

    // workspace layout (bf16 elements); ~103 MB total
    unsigned short* ws  = (unsigned short*)d_ws;
    const size_t NX = (size_t)B_ * S_ * D_;          // 8,388,608
    unsigned short* xb  = ws;                        // [16384][512]
    unsigned short* wtb = xb + NX;                   // [1536 n][512 k]
    unsigned short* qk  = wtb + 3 * D_ * D_;         // [16384][1024] (Q|K)
    unsigned short* vtb = qk + NX * 2;               // [b][d][s] = V^T

    // 1) converts
    convert_x4<<<dim3((unsigned)(NX / 4 / 256)), 256, 0, stream>>>(x, xb);
    convert_w<<<dim3(D_ * D_ / 256, 3), 256, 0, stream>>>(WQ, WK, WV, wtb);

    // 2) fused QKV projection, 256x256 tiles: grid 64 x 6 = 384.
    //    tn 0-3: Q|K -> qk; tn 4-5: V -> vtb transposed.
    gemm8<4, 2><<<dim3(384), 512, 0, stream>>>(
        xb, wtb, qk, vtb, D_, D_, D_, 2 * D_, /*ntn*/ 6);

    // 3) fused attention: scores + exp + rowsum + PV + normalize.
    //    8 batches x 32 q-panels = 256 blocks = 1 full round.
    fused_attn<<<dim3(256), 512, 0, stream>>>(
        qk, vtb, (float*)d_out, 0.04419417382415922f);
}

// Round 12
// 220.111 us; speedup vs baseline: 1.2173x; 1.0853x over previous
//
#include <hip/hip_runtime.h>
#include <cstdint>
#include <cstddef>

// Problem shape (fixed by the reference): B=8, S=2048, D=512, fp32 in/out.
#define B_ 8
#define S_ 2048
#define D_ 512

typedef float f32x4 __attribute__((ext_vector_type(4)));
typedef __bf16 bf16x8 __attribute__((ext_vector_type(8)));

// fp32 -> bf16 round-to-nearest-even
__device__ __forceinline__ unsigned short f2bf(float f) {
    unsigned u = __builtin_bit_cast(unsigned, f);
    u += 0x7FFFu + ((u >> 16) & 1u);
    return (unsigned short)(u >> 16);
}

// async global->LDS, 16 B/lane; LDS dest = wave-uniform base + lane*16.
__device__ __forceinline__ void gll16(const void* g, void* l) {
    __builtin_amdgcn_global_load_lds(
        (const __attribute__((address_space(1))) unsigned int*)g,
        (__attribute__((address_space(3))) unsigned int*)l, 16, 0, 0);
}

#define VMCNT(n) asm volatile("s_waitcnt vmcnt(%0)" :: "i"(n) : "memory")
#define LGKM0()  asm volatile("s_waitcnt lgkmcnt(0)" ::: "memory")
#define SBAR()   __builtin_amdgcn_s_barrier()
#define SCHED0() __builtin_amdgcn_sched_barrier(0)

// ---------------------------------------------------------------------------
// gemm8<4,2> — r12's 4-phase counted-vmcnt pipeline, QKV projection only.
// Unchanged from round 9 (passed, absmax 0.00195, total 225.6us).
// ---------------------------------------------------------------------------
template<int AMT, int BNT>
__global__ __launch_bounds__(512, 2) void gemm8(
    const unsigned short* __restrict__ A,
    const unsigned short* __restrict__ B,
    void* __restrict__ Cv,
    unsigned short* __restrict__ Cv2,
    int K, int lda, int ldb, int ldc, int ntn)
{
    constexpr int BM     = 64 * AMT;
    constexpr int BN     = 128 * BNT;
    constexpr int ABYTES = BM * 128;          // per-buf A bytes (BK=64 bf16)
    constexpr int BBYTES = BN * 128;
    constexpr int AH     = ABYTES / 2;
    constexpr int BH     = BBYTES / 2;
    constexpr int AGL    = AMT / 2;           // glls per wave per A-half
    constexpr int BGL    = BNT;
    constexpr int BUFB   = ABYTES + BBYTES;
    __shared__ __align__(16) char lds[2 * BUFB];

    const int tq  = blockIdx.x;
    const int tn  = tq % ntn;
    const int tm  = tq / ntn;
    const int m0   = tm * BM;
    const int n0   = tn * BN;
    const int tid  = threadIdx.x;
    const int lane = tid & 63;
    const int w    = tid >> 6;
    const int g2   = w >> 2;
    const int nb   = w & 3;

    const int lrow = lane >> 3;
    const int swz  = ((lane & 7) ^ lrow) << 3;
    const unsigned short* gA[2][AGL];
    const unsigned short* gB[2][BGL];
    #pragma unroll
    for (int h = 0; h < 2; ++h) {
        #pragma unroll
        for (int i = 0; i < AGL; ++i)
            gA[h][i] = A + (size_t)(m0 + h * (BM / 2) + (w * AGL + i) * 8 + lrow) * lda + swz;
        #pragma unroll
        for (int i = 0; i < BGL; ++i)
            gB[h][i] = B + (size_t)(n0 + h * (BN / 2) + (w * BGL + i) * 8 + lrow) * ldb + swz;
    }
    auto stA = [&](int bs, int h, int kof) {
        #pragma unroll
        for (int i = 0; i < AGL; ++i)
            gll16(gA[h][i] + kof, lds + bs * BUFB + h * AH + (w * AGL + i) * 1024);
    };
    auto stB = [&](int bs, int h, int kof) {
        #pragma unroll
        for (int i = 0; i < BGL; ++i)
            gll16(gB[h][i] + kof, lds + bs * BUFB + ABYTES + h * BH + (w * BGL + i) * 1024);
    };

    const int fr = lane & 15;
    const int gq = lane >> 4;
    const int c0 = (gq ^ (fr & 7)) << 4;
    int aoff[AMT], boff[BNT];
    #pragma unroll
    for (int ml = 0; ml < AMT; ++ml)
        aoff[ml] = (g2 * (16 * AMT) + ml * 16 + fr) * 128 + c0;
    #pragma unroll
    for (int nl = 0; nl < BNT; ++nl)
        boff[nl] = (nb * (16 * BNT) + nl * 16 + fr) * 128 + c0;

    bf16x8 af[2 * AMT], bLO[2 * BNT], bHI[2 * BNT];
    f32x4 acc[2 * AMT][2 * BNT] = {};

    auto ldA = [&](const char* Ab, int mh) {
        #pragma unroll
        for (int ml = 0; ml < AMT; ++ml)
            #pragma unroll
            for (int kk = 0; kk < 2; ++kk)
                af[ml * 2 + kk] = *(const bf16x8*)(Ab + mh * AH + (aoff[ml] ^ (kk << 6)));
    };
    auto ldB = [&](const char* Bb, int nh, bf16x8* bf) {
        #pragma unroll
        for (int nl = 0; nl < BNT; ++nl)
            #pragma unroll
            for (int kk = 0; kk < 2; ++kk)
                bf[nl * 2 + kk] = *(const bf16x8*)(Bb + nh * BH + (boff[nl] ^ (kk << 6)));
    };
    auto mma = [&](int mh, int nh, const bf16x8* bf) {
        __builtin_amdgcn_s_setprio(1);
        #pragma unroll
        for (int ml = 0; ml < AMT; ++ml)
            #pragma unroll
            for (int nl = 0; nl < BNT; ++nl)
                #pragma unroll
                for (int kk = 0; kk < 2; ++kk)
                    acc[mh * AMT + ml][nh * BNT + nl] =
                        __builtin_amdgcn_mfma_f32_16x16x32_bf16(
                            af[ml * 2 + kk], bf[nl * 2 + kk],
                            acc[mh * AMT + ml][nh * BNT + nl], 0, 0, 0);
        __builtin_amdgcn_s_setprio(0);
    };

    stA(0, 0, 0);  stB(0, 0, 0);
    stA(0, 1, 0);  stB(0, 1, 0);
    stA(1, 0, 64); stB(1, 0, 64);

    const int NT = K >> 6;
    for (int tt = 0; tt < NT; ++tt) {
        const int bs = tt & 1;
        const char* Ab = lds + bs * BUFB;
        const char* Bb = Ab + ABYTES;
        const bool last = (tt == NT - 1);

        if (!last) stA(bs ^ 1, 1, (tt + 1) << 6);
        if (last) { VMCNT(AGL + BGL); } else { VMCNT(6); }
        SBAR(); SCHED0();
        ldA(Ab, 0); ldB(Bb, 0, bLO);
        mma(0, 0, bLO);

        if (!last) stB(bs ^ 1, 1, (tt + 1) << 6);
        if (last) { VMCNT(0); } else { VMCNT(6); }
        SBAR(); SCHED0();
        ldB(Bb, 1, bHI);
        mma(0, 1, bHI);

        if (tt + 2 < NT) stA(bs, 0, (tt + 2) << 6);
        VMCNT(6);
        SBAR(); SCHED0();
        ldA(Ab, 1);
        mma(1, 0, bLO);

        if (tt + 2 < NT) stB(bs, 0, (tt + 2) << 6);
        VMCNT(6);
        SBAR(); SCHED0();
        mma(1, 1, bHI);
    }

    const int rb4 = gq << 2;
#define AB_(mt) ((((mt) / AMT) * (BM / 2)) + g2 * (16 * AMT) + ((mt) % AMT) * 16)
#define BB_(nt) ((((nt) / BNT) * (BN / 2)) + nb * (16 * BNT) + ((nt) % BNT) * 16)
    if (tn >= 4) {
        #pragma unroll
        for (int mt = 0; mt < 2 * AMT; ++mt) {
            const int s0q = m0 + AB_(mt) + rb4;
            const int b   = s0q >> 11;
            const int se  = s0q & (S_ - 1);
            #pragma unroll
            for (int nt = 0; nt < 2 * BNT; ++nt) {
                const int d = (n0 - 2 * D_) + BB_(nt) + fr;
                ushort4 u;
                u.x = f2bf(acc[mt][nt][0]);
                u.y = f2bf(acc[mt][nt][1]);
                u.z = f2bf(acc[mt][nt][2]);
                u.w = f2bf(acc[mt][nt][3]);
                *(ushort4*)&Cv2[((size_t)b * D_ + d) * S_ + se] = u;
            }
        }
    } else {
        unsigned short* C = (unsigned short*)Cv;
        #pragma unroll
        for (int mt = 0; mt < 2 * AMT; ++mt)
            #pragma unroll
            for (int nt = 0; nt < 2 * BNT; ++nt) {
                const int gc = n0 + BB_(nt) + fr;
                #pragma unroll
                for (int r = 0; r < 4; ++r)
                    C[(size_t)(m0 + AB_(mt) + rb4 + r) * ldc + gc] = f2bf(acc[mt][nt][r]);
            }
    }
#undef AB_
#undef BB_
}

// ---------------------------------------------------------------------------
// fused_attn v4 — EXACT round-9 restoration (measured: fused 107.7us, total
// 225.6us, clean counters FETCH 25.2MB / WRITE 33.8MB, no spill).
//
// r22 post-mortem: pf-hoist (demand ~248) re-spilled AND regressed codegen
// (+8.7us for ~2.4us of traffic). Envelope law calibrated across r18/r19/
// r21/r22: demand 184 clean, >=216 risk, >=248 spill. All read-reduction
// ideas need >=32 extra regs -> closed. 2-blocks/CU TLP needs <=128 regs
// (m69) but qreg 64 + acc_pv 64 = 128 alone -> closed. This kernel is at
// its practical plateau; restore verbatim.
//
// Schedule per kv-tile (ring-4, counted vmcnt, Q in 64 VGPRs):
//   stage:  P0:K2 | P1:K3,V0 | P2:V1 | P3:V2 | P4:V3 | P5:K0',K1'
//   vmcnt:  P0:4  | P1:4     | P2:8  | P3:8  | P4:4  | P5:0 (exact drain)
// Math (absmax 0.00195 verified): no-max-sub exp, bf16 P, fp32 accum,
// 1/rowsum at end.
// LDS: ring 4x32K @0 | P 16K @131072 | RS 512B @147456.
// Grid: 8 batches (XCD-pinned) x 32 q-panels = 256 blocks, 8 waves.
// ---------------------------------------------------------------------------
__global__ __launch_bounds__(512, 2) void fused_attn(
    const unsigned short* __restrict__ qk,   // [B*S][1024] rows: Q|K
    const unsigned short* __restrict__ vtb,  // [B][512][2048] = V^T
    float* __restrict__ out,                 // [B][S][512]
    float scale)
{
    __shared__ __align__(16) char lds[148480];
    char* const RING = lds;                       // 4 x 32KB chunk slots
    char* const PB   = lds + 131072;              // P [64 q][128 kv], 256B rows
    float* const RS  = (float*)(lds + 147456);    // rs[2][64]

    const int lin = blockIdx.x;
    const int bz  = lin & 7;                      // batch -> XCD pin
    const int q0  = (lin >> 3) * 64;              // q-panel base
    const int tid = threadIdx.x;
    const int lane = tid & 63;
    const int w   = tid >> 6;
    const int fr  = lane & 15;
    const int gq  = lane >> 4;
    const int g2  = w >> 2;                       // kv-half (S-phase)
    const int nb  = w & 3;                        // q-quarter (S-phase)
    const int k7  = fr & 7;

    // 256B-row staging geometry: off = tid*16 + i*8192.
    int row4[4], sc4[4];
    #pragma unroll
    for (int i = 0; i < 4; ++i) {
        const int off = tid * 16 + i * 8192;
        row4[i] = off >> 8;
        sc4[i]  = ((((off >> 4) & 15) ^ (row4[i] & 7)) << 3);
    }
    const size_t qrowb = (size_t)bz * S_;

    auto stK = [&](int slot, int kv0, int j) {    // K chunk j: [128 kv][128 d]
        #pragma unroll
        for (int i = 0; i < 4; ++i)
            gll16(qk + (qrowb + kv0 + row4[i]) * 1024 + 512 + j * 128 + sc4[i],
                  RING + slot * 32768 + tid * 16 + i * 8192);
    };
    auto stV = [&](int slot, int kv0, int c) {    // V chunk c: [128 d][128 kv]
        #pragma unroll
        for (int i = 0; i < 4; ++i)
            gll16(vtb + ((size_t)bz * D_ + c * 128 + row4[i]) * S_ + kv0 + sc4[i],
                  RING + slot * 32768 + tid * 16 + i * 8192);
    };

    // ---- Q -> registers: qreg[c] = B-frag [col=q=nb*16+fr][k-chunk c] ----
    bf16x8 qreg[16];
    #pragma unroll
    for (int c = 0; c < 16; ++c)
        qreg[c] = *(const bf16x8*)(
            qk + (qrowb + q0 + nb * 16 + fr) * 1024 + c * 32 + gq * 8);
    SCHED0();

    f32x4 acc_pv[4][4] = {};                      // [d-chunk][q-16-block]
    float rsl = 0.f;

    stK(0, 0, 0); stK(1, 0, 1);                   // prologue: K0->s0, K1->s1
    SCHED0();

    for (int kvi = 0; kvi < 16; ++kvi) {
        const int kv0 = kvi * 128;
        f32x4 acc_s[4] = {};                      // [mt: kv16-block in half]

        // ---- S-phases j=0..3 ----
        #pragma unroll
        for (int j = 0; j < 4; ++j) {
            if (j < 2) { VMCNT(4); } else { VMCNT(8); }
            SBAR(); SCHED0();
            if      (j == 0) stK(2, kv0, 2);
            else if (j == 1) { stK(3, kv0, 3); stV(0, kv0, 0); }
            else if (j == 2) stV(1, kv0, 1);
            else             stV(2, kv0, 2);
            SCHED0();
            const char* Kb = RING + j * 32768;
            __builtin_amdgcn_s_setprio(1);
            #pragma unroll
            for (int kk = 0; kk < 4; ++kk) {
                const int ch = ((kk * 4 + gq) ^ k7) << 4;
                #pragma unroll
                for (int mt = 0; mt < 4; ++mt) {
                    const bf16x8 kf = *(const bf16x8*)(
                        Kb + (g2 * 64 + mt * 16 + fr) * 256 + ch);
                    acc_s[mt] = __builtin_amdgcn_mfma_f32_16x16x32_bf16(
                        kf, qreg[j * 4 + kk], acc_s[mt], 0, 0, 0);
                }
            }
            __builtin_amdgcn_s_setprio(0);
        }

        // ---- P4 (PV-a): exp + P-write | force V0,V1 | stage V3 ----
        #pragma unroll
        for (int mt = 0; mt < 4; ++mt) {
            float p0 = __expf(acc_s[mt][0] * scale);
            float p1 = __expf(acc_s[mt][1] * scale);
            float p2 = __expf(acc_s[mt][2] * scale);
            float p3 = __expf(acc_s[mt][3] * scale);
            rsl += (p0 + p1) + (p2 + p3);
            ushort4 u;
            u.x = f2bf(p0); u.y = f2bf(p1); u.z = f2bf(p2); u.w = f2bf(p3);
            const int row   = nb * 16 + fr;
            const int chunk = g2 * 8 + mt * 2 + (gq >> 1);
            *(ushort4*)(PB + row * 256 + ((chunk ^ k7) << 4) + (gq & 1) * 8) = u;
        }
        LGKM0();           // my P writes visible
        VMCNT(4);          // force V0,V1 (leaves V2,V3-slot flying)
        SBAR(); SCHED0();  // everyone's P + V0,V1 ready
        stV(3, kv0, 3);
        SCHED0();
        __builtin_amdgcn_s_setprio(1);
        #pragma unroll
        for (int ks = 0; ks < 4; ++ks) {
            const int ch = ((ks * 4 + gq) ^ k7) << 4;
            const bf16x8 vf0 = *(const bf16x8*)(RING + (w * 16 + fr) * 256 + ch);
            const bf16x8 vf1 = *(const bf16x8*)(RING + 32768 + (w * 16 + fr) * 256 + ch);
            #pragma unroll
            for (int nt2 = 0; nt2 < 4; ++nt2) {
                const bf16x8 pf = *(const bf16x8*)(PB + (nt2 * 16 + fr) * 256 + ch);
                acc_pv[0][nt2] = __builtin_amdgcn_mfma_f32_16x16x32_bf16(
                    vf0, pf, acc_pv[0][nt2], 0, 0, 0);
                acc_pv[1][nt2] = __builtin_amdgcn_mfma_f32_16x16x32_bf16(
                    vf1, pf, acc_pv[1][nt2], 0, 0, 0);
            }
        }
        __builtin_amdgcn_s_setprio(0);

        // ---- P5 (PV-b): exact drain V2,V3 | stage K0',K1' ----
        VMCNT(0);
        SBAR(); SCHED0();
        if (kvi < 15) { stK(0, kv0 + 128, 0); stK(1, kv0 + 128, 1); }
        SCHED0();
        __builtin_amdgcn_s_setprio(1);
        #pragma unroll
        for (int ks = 0; ks < 4; ++ks) {
            const int ch = ((ks * 4 + gq) ^ k7) << 4;
            const bf16x8 vf2 = *(const bf16x8*)(RING + 65536 + (w * 16 + fr) * 256 + ch);
            const bf16x8 vf3 = *(const bf16x8*)(RING + 98304 + (w * 16 + fr) * 256 + ch);
            #pragma unroll
            for (int nt2 = 0; nt2 < 4; ++nt2) {
                const bf16x8 pf = *(const bf16x8*)(PB + (nt2 * 16 + fr) * 256 + ch);
                acc_pv[2][nt2] = __builtin_amdgcn_mfma_f32_16x16x32_bf16(
                    vf2, pf, acc_pv[2][nt2], 0, 0, 0);
                acc_pv[3][nt2] = __builtin_amdgcn_mfma_f32_16x16x32_bf16(
                    vf3, pf, acc_pv[3][nt2], 0, 0, 0);
            }
        }
        __builtin_amdgcn_s_setprio(0);
    }

    // ---- rowsum reduce: fold gq axis; RS[g2][q], unique writers ----
    rsl += __shfl_xor(rsl, 16);
    rsl += __shfl_xor(rsl, 32);
    if (lane < 16) RS[g2 * 64 + nb * 16 + lane] = rsl;
    __syncthreads();

    // ---- normalize + store O[b][q0+q][d], float4 along d ----
    #pragma unroll
    for (int nt2 = 0; nt2 < 4; ++nt2) {
        const int q = nt2 * 16 + fr;
        const float inv = __builtin_amdgcn_rcpf(RS[q] + RS[64 + q]);
        float* op = out + ((qrowb + q0 + q) * D_);
        #pragma unroll
        for (int c = 0; c < 4; ++c) {
            const int d0 = c * 128 + w * 16 + gq * 4;
            float4 o;
            o.x = acc_pv[c][nt2][0] * inv;
            o.y = acc_pv[c][nt2][1] * inv;
            o.z = acc_pv[c][nt2][2] * inv;
            o.w = acc_pv[c][nt2][3] * inv;
            *(float4*)(op + d0) = o;
        }
    }
}

// ---------------------------------------------------------------------------
// Merged converts: one dispatch covers both x (fp32->bf16, 4/thread) and
// the three W transposes. Saves one launch gap vs two kernels; the parts
// are independent and each block executes exactly one.
//   blocks 0..8191:        xb[i..i+3] = bf16(x[i..i+3])
//   blocks 8192..11263:    wtb (3 x 1024 blocks): W[d][e] -> WT[e][d]
// ---------------------------------------------------------------------------
__global__ __launch_bounds__(256) void convert_all(
    const float* __restrict__ x,
    const float* __restrict__ WQ,
    const float* __restrict__ WK,
    const float* __restrict__ WV,
    unsigned short* __restrict__ xb,
    unsigned short* __restrict__ wtb)
{
    const int b = blockIdx.x;
    if (b < 8192) {
        const size_t i = ((size_t)b * 256 + threadIdx.x) * 4;
        const float4 f = *(const float4*)(x + i);
        ushort4 u;
        u.x = f2bf(f.x); u.y = f2bf(f.y); u.z = f2bf(f.z); u.w = f2bf(f.w);
        *(ushort4*)(xb + i) = u;
    } else {
        const int bb   = b - 8192;                 // 0..3071
        const int wsel = bb >> 10;                 // 0..2
        const int o    = (bb & 1023) * 256 + threadIdx.x;   // 0..D*D-1
        const float* W = wsel == 0 ? WQ : (wsel == 1 ? WK : WV);
        const int e = o >> 9, d = o & (D_ - 1);
        wtb[(size_t)wsel * D_ * D_ + o] = f2bf(W[d * D_ + e]);
    }
}

// ---------------------------------------------------------------------------
extern "C" void kernel_launch(void* const* d_in, const int* in_sizes, int n_in,
                              void* d_out, int out_size, void* d_ws, size_t ws_size,
                              hipStream_t stream)
{
    const float* x  = (const float*)d_in[0];
    const float* WQ = (const float*)d_in[1];
    const float* WK = (const float*)d_in[2];
    const float* WV = (const float*)d_in[3];

    // workspace layout (bf16 elements); ~103 MB total
    unsigned short* ws  = (unsigned short*)d_ws;
    const size_t NX = (size_t)B_ * S_ * D_;          // 8,388,608
    unsigned short* xb  = ws;                        // [16384][512]
    unsigned short* wtb = xb + NX;                   // [1536 n][512 k]
    unsigned short* qk  = wtb + 3 * D_ * D_;         // [16384][1024] (Q|K)
    unsigned short* vtb = qk + NX * 2;               // [b][d][s] = V^T

    // 1) converts (single dispatch: 8192 x-blocks + 3072 w-blocks)
    convert_all<<<dim3(11264), 256, 0, stream>>>(x, WQ, WK, WV, xb, wtb);

    // 2) fused QKV projection, 256x256 tiles: grid 64 x 6 = 384.
    //    tn 0-3: Q|K -> qk; tn 4-5: V -> vtb transposed.
    gemm8<4, 2><<<dim3(384), 512, 0, stream>>>(
        xb, wtb, qk, vtb, D_, D_, D_, 2 * D_, /*ntn*/ 6);

    // 3) fused attention: scores + exp + rowsum + PV + normalize.
    //    8 batches x 32 q-panels = 256 blocks = 1 full round.
    fused_attn<<<dim3(256), 512, 0, stream>>>(
        qk, vtb, (float*)d_out, 0.04419417382415922f);
}